// Round 2
// baseline (393.913 us; speedup 1.0000x reference)
//
#include <hip/hip_runtime.h>

// XGBoost forest inference: B=50000, F=256, T=1000, depth=6, 127 nodes/tree.
// v2: LDS-pipe is the bottleneck resource -> move tree levels 0-2 and the
// leaf read to the (idle) VMEM pipe (L2-resident, <=8 distinct addrs/wave);
// LDS keeps only the x-gather (transposed, bank=s%32, conflict-free) and
// mid-levels 3-5 (int2, b64). 256-thr blocks (32 samples x 8 tree-lanes),
// 61KB LDS -> 2 blocks/CU, grid=1563 -> dynamic load balance (fixes the
// 782/256=3.05->4 makespan cliff of v1). Tree tile staging is reg-double-
// buffered: issue loads for tile t+1, walk tile t, barrier, write, barrier.

#define NFEAT    256
#define NTREES   1000
#define NNODES   127
#define SPB      32      // samples per block
#define TLANES   8       // tree lanes (tid>>5)
#define TILE_T   64      // trees per LDS tile
#define TREC     112     // dwords per tree in LDS: 56 int2 (nodes 7..62)
#define SPT      28      // float4 staging slots per tree
#define NTHREADS 256
#define MAXR     7       // staging rounds: 64*28/256

__device__ __forceinline__ void stage_load(const int* __restrict__ gIdx,
                                           const float* __restrict__ gCond,
                                           int tb, int nT, int tid, int4* st)
{
    const int tot = nT * SPT;
#pragma unroll
    for (int r = 0; r < MAXR; ++r) {
        const int slot = tid + r * NTHREADS;
        if (slot < tot) {
            const int tl   = slot / SPT;
            const int off4 = slot - tl * SPT;
            const int g    = (tb + tl) * NNODES + 7 + 2 * off4;
            st[r] = make_int4(gIdx[g],     __float_as_int(gCond[g]),
                              gIdx[g + 1], __float_as_int(gCond[g + 1]));
        }
    }
}

__device__ __forceinline__ void stage_write(int* __restrict__ treeLds,
                                            int nT, int tid, const int4* st)
{
    const int tot = nT * SPT;
#pragma unroll
    for (int r = 0; r < MAXR; ++r) {
        const int slot = tid + r * NTHREADS;
        if (slot < tot) {
            const int tl   = slot / SPT;
            const int off4 = slot - tl * SPT;
            *reinterpret_cast<int4*>(&treeLds[tl * TREC + 4 * off4]) = st[r];
        }
    }
}

template <int W>
__device__ __forceinline__ void walk_trees(const int* __restrict__ gIdx,
                                           const float* __restrict__ gCond,
                                           const int* __restrict__ treeLds,
                                           const float* __restrict__ xs,
                                           int tb, int tlane, int k, float& acc)
{
    int node[W], gbase[W], lbase[W];
#pragma unroll
    for (int j = 0; j < W; ++j) {
        const int tl = tlane + (k + j) * TLANES;
        gbase[j] = (tb + tl) * NNODES;
        lbase[j] = tl * TREC;
        node[j]  = 0;
    }
    // levels 0-2: VMEM, L2-resident, <=2 trees x 4 nodes distinct per wave
#pragma unroll
    for (int d = 0; d < 3; ++d) {
#pragma unroll
        for (int j = 0; j < W; ++j) {
            const int   g  = gbase[j] + node[j];
            const int   f  = gIdx[g];
            const float c  = gCond[g];
            const float xv = xs[f * SPB];
            node[j] = (node[j] << 1) + 1 + (int)((xv - c) > 0.0f);
        }
    }
    // levels 3-5: LDS int2 (b64), nodes 7..62
#pragma unroll
    for (int d = 3; d < 6; ++d) {
#pragma unroll
        for (int j = 0; j < W; ++j) {
            const int2 nd = *reinterpret_cast<const int2*>(
                &treeLds[lbase[j] + 2 * (node[j] - 7)]);
            const float xv = xs[nd.x * SPB];
            node[j] = (node[j] << 1) + 1 +
                      (int)((xv - __int_as_float(nd.y)) > 0.0f);
        }
    }
    // leaf: VMEM gather (256B/tree contiguous region, L2-resident)
#pragma unroll
    for (int j = 0; j < W; ++j)
        acc += gCond[gbase[j] + node[j]];
}

__global__ __launch_bounds__(NTHREADS, 2) void xgb_forest_kernel(
    const float* __restrict__ x,
    const int*   __restrict__ split_idx,
    const float* __restrict__ split_cond,
    const float* __restrict__ base_score,
    float* __restrict__ out, int B)
{
    __shared__ float xT[NFEAT * SPB];         // 32 KB, transposed [feat][sample]
    __shared__ int   treeLds[TILE_T * TREC];  // 28 KB, nodes 7..62 as int2
    __shared__ float partials[TLANES * SPB];  //  1 KB

    const int tid   = threadIdx.x;
    const int sbase = blockIdx.x * SPB;

    // ---- stage x transposed: lane->row = idx&31 keeps LDS writes 2-way ----
#pragma unroll
    for (int r = 0; r < 8; ++r) {
        const int idx = tid + r * NTHREADS;
        const int sl  = idx & (SPB - 1);
        const int c4  = idx >> 5;             // 0..63 float4-column
        float4 v = make_float4(0.f, 0.f, 0.f, 0.f);
        if (sbase + sl < B)
            v = *reinterpret_cast<const float4*>(
                &x[(size_t)(sbase + sl) * NFEAT + c4 * 4]);
        xT[(c4 * 4 + 0) * SPB + sl] = v.x;
        xT[(c4 * 4 + 1) * SPB + sl] = v.y;
        xT[(c4 * 4 + 2) * SPB + sl] = v.z;
        xT[(c4 * 4 + 3) * SPB + sl] = v.w;
    }

    int4 st[MAXR];
    stage_load(split_idx, split_cond, 0, TILE_T, tid, st);
    stage_write(treeLds, TILE_T, tid, st);
    __syncthreads();

    const int s     = tid & (SPB - 1);
    const int tlane = tid >> 5;
    const float* xs = &xT[s];
    float acc = 0.0f;

    const int ntiles = (NTREES + TILE_T - 1) / TILE_T;   // 16 (last = 40 trees)
    for (int t = 0; t < ntiles; ++t) {
        const int tb  = t * TILE_T;
        const int nT  = min(TILE_T, NTREES - tb);
        const int nTn = (t + 1 < ntiles) ? min(TILE_T, NTREES - tb - TILE_T) : 0;

        if (nTn) stage_load(split_idx, split_cond, tb + TILE_T, nTn, tid, st);

        const int kmax = ((nT - 1 - tlane) >> 3) + 1;
        int k = 0;
        for (; k + 8 <= kmax; k += 8)
            walk_trees<8>(split_idx, split_cond, treeLds, xs, tb, tlane, k, acc);
        for (; k + 4 <= kmax; k += 4)
            walk_trees<4>(split_idx, split_cond, treeLds, xs, tb, tlane, k, acc);
        for (; k < kmax; ++k)
            walk_trees<1>(split_idx, split_cond, treeLds, xs, tb, tlane, k, acc);

        __syncthreads();
        if (nTn) stage_write(treeLds, nTn, tid, st);
        __syncthreads();
    }

    partials[tlane * SPB + s] = acc;
    __syncthreads();
    if (tid < SPB) {
        float r = base_score[0];
#pragma unroll
        for (int l = 0; l < TLANES; ++l) r += partials[l * SPB + tid];
        if (sbase + tid < B) out[sbase + tid] = r;
    }
}

extern "C" void kernel_launch(void* const* d_in, const int* in_sizes, int n_in,
                              void* d_out, int out_size, void* d_ws, size_t ws_size,
                              hipStream_t stream)
{
    const float* x          = (const float*)d_in[0];
    const int*   split_idx  = (const int*)d_in[1];
    const float* split_cond = (const float*)d_in[2];
    const float* base_score = (const float*)d_in[3];
    float*       out        = (float*)d_out;

    const int B    = out_size;                    // 50000
    const int grid = (B + SPB - 1) / SPB;         // 1563

    xgb_forest_kernel<<<grid, NTHREADS, 0, stream>>>(x, split_idx, split_cond,
                                                     base_score, out, B);
}

// Round 3
// 278.952 us; speedup vs baseline: 1.4121x; 1.4121x over previous
//
#include <hip/hip_runtime.h>

// XGBoost forest inference: B=50000, F=256, T=1000, depth=6, 127 nodes/tree.
// v3: LDS-issue is the pacer (v1 model confirmed: 91cy/visit). Offload tree
// levels 0-2 to the SCALAR pipe: nodes 0..6 are wave-uniform -> s_load via
// readfirstlane-derived addresses, per-lane select via cndmask (VALU has 2x
// headroom). Leaf stored as separate f32 LDS array (b32 not b64). Per-visit
// LDS: 91 -> ~65cy. Makespan: split trees 2-ways (1564 blocks, 6.1/CU -> 7
// rounds vs v1's 4-of-3.05) combined with atomicAdd after an init kernel.
// v2 lesson: NEVER per-lane divergent VMEM for tree nodes.

#define NFEAT   256
#define NNODES  127
#define NTREES  1000
#define SPB     64      // samples per block (= lanes per wave)
#define NTH     512     // 8 waves
#define TLANES  8       // tree lanes (tid>>6)
#define TILE_T  64      // trees per LDS tile
#define TREC    176     // dwords per tree in LDS: 56 int2 (nodes 7..62) + 64 leaf f32
#define NSPLIT  2
#define TSPLIT  500     // trees per split
#define MID_R   7       // TILE_T*56/NTH
#define LEAF_R  8       // TILE_T*64/NTH

__global__ void xgb_init_kernel(const float* __restrict__ base_score,
                                float* __restrict__ out, int B)
{
    const int i = blockIdx.x * 256 + threadIdx.x;
    if (i < B) out[i] = base_score[0];
}

__device__ __forceinline__ void stage_load(const int* __restrict__ gIdx,
                                           const float* __restrict__ gCond,
                                           int tb, int nT, int tid,
                                           int2* stm, float* stl)
{
    const int totm = nT * 56;
#pragma unroll
    for (int r = 0; r < MID_R; ++r) {
        const int slot = tid + r * NTH;
        if (slot < totm) {
            const int tl  = slot / 56;
            const int off = slot - tl * 56;
            const int g   = (tb + tl) * NNODES + 7 + off;
            stm[r] = make_int2(gIdx[g], __float_as_int(gCond[g]));
        }
    }
    const int totl = nT * 64;
#pragma unroll
    for (int r = 0; r < LEAF_R; ++r) {
        const int slot = tid + r * NTH;
        if (slot < totl) {
            const int tl  = slot >> 6;
            const int off = slot & 63;
            stl[r] = gCond[(tb + tl) * NNODES + 63 + off];
        }
    }
}

__device__ __forceinline__ void stage_write(int* __restrict__ lds, int nT, int tid,
                                            const int2* stm, const float* stl)
{
    const int totm = nT * 56;
#pragma unroll
    for (int r = 0; r < MID_R; ++r) {
        const int slot = tid + r * NTH;
        if (slot < totm) {
            const int tl  = slot / 56;
            const int off = slot - tl * 56;
            *reinterpret_cast<int2*>(&lds[tl * TREC + 2 * off]) = stm[r];
        }
    }
    const int totl = nT * 64;
#pragma unroll
    for (int r = 0; r < LEAF_R; ++r) {
        const int slot = tid + r * NTH;
        if (slot < totl) {
            const int tl  = slot >> 6;
            const int off = slot & 63;
            lds[tl * TREC + 112 + off] = __float_as_int(stl[r]);
        }
    }
}

template <int W>
__device__ __forceinline__ void walk(const int* __restrict__ gIdx,
                                     const float* __restrict__ gCond,
                                     const int* __restrict__ lds,
                                     const float* __restrict__ xs,
                                     int tb, int tlane, int k, float& acc)
{
    int node[W], lb[W];
#pragma unroll
    for (int j = 0; j < W; ++j) {
        const int tl = tlane + (k + j) * TLANES;   // tile-local tree
        lb[j] = tl * TREC;
        // wave-uniform tree base -> scalar loads of nodes 0..6
        const int g = __builtin_amdgcn_readfirstlane((tb + tl) * NNODES);
        const int   f0 = gIdx[g + 0];  const float c0 = gCond[g + 0];
        const int   f1 = gIdx[g + 1];  const float c1 = gCond[g + 1];
        const int   f2 = gIdx[g + 2];  const float c2 = gCond[g + 2];
        const int   f3 = gIdx[g + 3];  const float c3 = gCond[g + 3];
        const int   f4 = gIdx[g + 4];  const float c4 = gCond[g + 4];
        const int   f5 = gIdx[g + 5];  const float c5 = gCond[g + 5];
        const int   f6 = gIdx[g + 6];  const float c6 = gCond[g + 6];
        // level 0
        const bool b0 = (xs[f0 * SPB] - c0) > 0.0f;
        // level 1: nodes {1,2}
        const int   fa = b0 ? f2 : f1;
        const float ca = b0 ? c2 : c1;
        const bool b1 = (xs[fa * SPB] - ca) > 0.0f;
        // level 2: nodes {3,4,5,6}
        const int   fb = b0 ? (b1 ? f6 : f5) : (b1 ? f4 : f3);
        const float cb = b0 ? (b1 ? c6 : c5) : (b1 ? c4 : c3);
        const bool b2 = (xs[fb * SPB] - cb) > 0.0f;
        node[j] = 7 + 4 * (int)b0 + 2 * (int)b1 + (int)b2;   // 7..14
    }
    // levels 3-5: LDS int2 (nodes 7..62)
#pragma unroll
    for (int d = 3; d < 6; ++d) {
#pragma unroll
        for (int j = 0; j < W; ++j) {
            const int2 nd = *reinterpret_cast<const int2*>(
                &lds[lb[j] + 2 * (node[j] - 7)]);
            node[j] = 2 * node[j] + 1 +
                      (int)((xs[nd.x * SPB] - __int_as_float(nd.y)) > 0.0f);
        }
    }
    // leaf: f32 LDS array (b32)
#pragma unroll
    for (int j = 0; j < W; ++j)
        acc += __int_as_float(lds[lb[j] + 112 + (node[j] - 63)]);
}

__global__ __launch_bounds__(NTH, 1) void xgb_forest_kernel(
    const float* __restrict__ x,
    const int*   __restrict__ split_idx,
    const float* __restrict__ split_cond,
    float* __restrict__ out, int B)
{
    __shared__ float xT[NFEAT * SPB];        // 64 KB, transposed [feat][sample]
    __shared__ int   treeLds[TILE_T * TREC]; // 44 KB, mid int2 + leaf f32
    __shared__ float partials[TLANES * SPB]; //  2 KB

    const int tid   = threadIdx.x;
    const int sbase = (blockIdx.x >> 1) * SPB;
    const int t0    = (blockIdx.x & 1) * TSPLIT;

    // ---- stage x tile, transposed (bank = sample%32 on gather) ----
    {
        const int sq = tid & 15;
        const int cg = tid >> 4;               // 0..31
        for (int rg = 0; rg < 4; ++rg) {
            const int  sl = rg * 16 + sq;
            const bool ok = (sbase + sl) < B;
            for (int ci = 0; ci < 2; ++ci) {
                const int c4 = ci * 32 + cg;
                float4 v = make_float4(0.f, 0.f, 0.f, 0.f);
                if (ok)
                    v = *reinterpret_cast<const float4*>(
                        &x[(size_t)(sbase + sl) * NFEAT + c4 * 4]);
                xT[(c4 * 4 + 0) * SPB + sl] = v.x;
                xT[(c4 * 4 + 1) * SPB + sl] = v.y;
                xT[(c4 * 4 + 2) * SPB + sl] = v.z;
                xT[(c4 * 4 + 3) * SPB + sl] = v.w;
            }
        }
    }

    int2  stm[MID_R];
    float stl[LEAF_R];
    stage_load(split_idx, split_cond, t0, TILE_T, tid, stm, stl);
    stage_write(treeLds, TILE_T, tid, stm, stl);
    __syncthreads();

    const int s     = tid & 63;
    const int tlane = tid >> 6;
    const float* xs = &xT[s];
    float acc = 0.0f;

    const int ntiles = (TSPLIT + TILE_T - 1) / TILE_T;   // 8 (last = 52 trees)
    for (int t = 0; t < ntiles; ++t) {
        const int tb  = t0 + t * TILE_T;
        const int nT  = min(TILE_T, t0 + TSPLIT - tb);
        const int nTn = (t + 1 < ntiles) ? min(TILE_T, TSPLIT - (t + 1) * TILE_T) : 0;

        if (nTn) stage_load(split_idx, split_cond, tb + TILE_T, nTn, tid, stm, stl);

        const int kmax = ((nT - 1 - tlane) >> 3) + 1;   // wave-uniform
        int k = 0;
        for (; k + 4 <= kmax; k += 4)
            walk<4>(split_idx, split_cond, treeLds, xs, tb, tlane, k, acc);
        for (; k < kmax; ++k)
            walk<1>(split_idx, split_cond, treeLds, xs, tb, tlane, k, acc);

        __syncthreads();
        if (nTn) stage_write(treeLds, nTn, tid, stm, stl);
        __syncthreads();
    }

    partials[tlane * SPB + s] = acc;
    __syncthreads();
    if (tid < SPB && sbase + tid < B) {
        float r = 0.0f;
#pragma unroll
        for (int l = 0; l < TLANES; ++l) r += partials[l * SPB + tid];
        atomicAdd(&out[sbase + tid], r);   // 2 adds/elem; ulp noise << 2.7 thr
    }
}

extern "C" void kernel_launch(void* const* d_in, const int* in_sizes, int n_in,
                              void* d_out, int out_size, void* d_ws, size_t ws_size,
                              hipStream_t stream)
{
    const float* x          = (const float*)d_in[0];
    const int*   split_idx  = (const int*)d_in[1];
    const float* split_cond = (const float*)d_in[2];
    const float* base_score = (const float*)d_in[3];
    float*       out        = (float*)d_out;

    const int B = out_size;                               // 50000
    xgb_init_kernel<<<(B + 255) / 256, 256, 0, stream>>>(base_score, out, B);

    const int grid = ((B + SPB - 1) / SPB) * NSPLIT;      // 1564
    xgb_forest_kernel<<<grid, NTH, 0, stream>>>(x, split_idx, split_cond, out, B);
}

// Round 4
// 205.288 us; speedup vs baseline: 1.9188x; 1.3588x over previous
//
#include <hip/hip_runtime.h>

// XGBoost forest inference: B=50000, F=256, T=1000, depth=6, 127 nodes/tree.
// v4: two-pipe split. x-gathers stay in LDS (transposed xT, bank=s%32,
// conflict-free; per-lane random global gather is forbidden -- v2 lesson).
// Tree-node reads move to VMEM from a PACKED int2 array in d_ws (1 load per
// level; level-d read spans only 1-5 cache lines since nodes are heap-
// adjacent; trees = 1MB -> L2-resident per XCD). LDS/visit: 91cy -> 35cy.
// Latency coverage: 16 waves/CU (2 blocks x 8 waves, LDS=66KB) x W=8 trees
// in flight = 128 chains (v2 failed with 64 + 2-array reads). No LDS tree
// staging at all. Makespan: 1564 units (tree-split 2 + atomicAdd, validated
// in v3), 2-resident -> ~x1.07 quantization vs v1's x1.31.

#define NFEAT   256
#define NNODES  127
#define NTREES  1000
#define SPB     64      // samples per block (= lanes per wave)
#define NTH     512     // 8 waves
#define TLANES  8       // tree lanes (tid>>6)
#define NSPLIT  2
#define TSPLIT  500     // trees per split unit

__global__ void xgb_init_kernel(const float* __restrict__ base_score,
                                float* __restrict__ out, int B)
{
    const int i = blockIdx.x * 256 + threadIdx.x;
    if (i < B) out[i] = base_score[0];
}

__global__ void xgb_pack_kernel(const int* __restrict__ idx,
                                const float* __restrict__ cond,
                                int2* __restrict__ packed, int n)
{
    const int i = blockIdx.x * 256 + threadIdx.x;
    if (i < n) packed[i] = make_int2(idx[i], __float_as_int(cond[i]));
}

template <int W, bool PACKED>
__device__ __forceinline__ void walk(const int2* __restrict__ tree,
                                     const int* __restrict__ gIdx,
                                     const float* __restrict__ gCond,
                                     const float* __restrict__ xs,
                                     int t0, int tlane, int k, float& acc)
{
    int node[W], o[W];
#pragma unroll
    for (int j = 0; j < W; ++j) {
        node[j] = 0;
        o[j] = (t0 + tlane + (k + j) * TLANES) * NNODES;
    }
#pragma unroll
    for (int d = 0; d < 6; ++d) {
        int   f[W];
        float c[W];
        if (PACKED) {
            int2 nd[W];
#pragma unroll
            for (int j = 0; j < W; ++j) nd[j] = tree[o[j] + node[j]];
#pragma unroll
            for (int j = 0; j < W; ++j) { f[j] = nd[j].x; c[j] = __int_as_float(nd[j].y); }
        } else {
#pragma unroll
            for (int j = 0; j < W; ++j) f[j] = gIdx[o[j] + node[j]];
#pragma unroll
            for (int j = 0; j < W; ++j) c[j] = gCond[o[j] + node[j]];
        }
#pragma unroll
        for (int j = 0; j < W; ++j) {
            const float xv = xs[f[j] * SPB];           // LDS, conflict-free
            node[j] = 2 * node[j] + 1 + (int)((xv - c[j]) > 0.0f);
        }
    }
#pragma unroll
    for (int j = 0; j < W; ++j)
        acc += PACKED ? __int_as_float(tree[o[j] + node[j]].y)
                      : gCond[o[j] + node[j]];
}

template <bool PACKED>
__global__ __launch_bounds__(NTH, 4) void xgb_forest_kernel(
    const float* __restrict__ x,
    const int*   __restrict__ split_idx,
    const float* __restrict__ split_cond,
    const int2*  __restrict__ tree,
    float* __restrict__ out, int B)
{
    __shared__ float xT[NFEAT * SPB];        // 64 KB, transposed [feat][sample]
    __shared__ float partials[TLANES * SPB]; //  2 KB

    const int tid   = threadIdx.x;
    const int sbase = (blockIdx.x >> 1) * SPB;
    const int t0    = (blockIdx.x & 1) * TSPLIT;

    // ---- stage x tile, transposed. Wave-instr = 16 rows x one 64B line/row
    // (full-line use); LDS writes 4-way on 16 banks (minor, 256 instrs). ----
    {
        const int sq = tid & 15;
        const int cg = tid >> 4;               // 0..31
        for (int rg = 0; rg < 4; ++rg) {
            const int  sl = rg * 16 + sq;
            const bool ok = (sbase + sl) < B;
            for (int ci = 0; ci < 2; ++ci) {
                const int c4 = ci * 32 + cg;
                float4 v = make_float4(0.f, 0.f, 0.f, 0.f);
                if (ok)
                    v = *reinterpret_cast<const float4*>(
                        &x[(size_t)(sbase + sl) * NFEAT + c4 * 4]);
                xT[(c4 * 4 + 0) * SPB + sl] = v.x;
                xT[(c4 * 4 + 1) * SPB + sl] = v.y;
                xT[(c4 * 4 + 2) * SPB + sl] = v.z;
                xT[(c4 * 4 + 3) * SPB + sl] = v.w;
            }
        }
    }
    __syncthreads();

    const int s     = tid & 63;
    const int tlane = tid >> 6;
    const float* xs = &xT[s];
    float acc = 0.0f;

    // trees t0 + tlane + k*8, k < kmax (wave-uniform: 63 or 62)
    const int kmax = ((TSPLIT - 1 - tlane) >> 3) + 1;
    int k = 0;
    for (; k + 8 <= kmax; k += 8)
        walk<8, PACKED>(tree, split_idx, split_cond, xs, t0, tlane, k, acc);
    for (; k + 4 <= kmax; k += 4)
        walk<4, PACKED>(tree, split_idx, split_cond, xs, t0, tlane, k, acc);
    for (; k + 2 <= kmax; k += 2)
        walk<2, PACKED>(tree, split_idx, split_cond, xs, t0, tlane, k, acc);
    for (; k < kmax; ++k)
        walk<1, PACKED>(tree, split_idx, split_cond, xs, t0, tlane, k, acc);

    partials[tlane * SPB + s] = acc;
    __syncthreads();
    if (tid < SPB && sbase + tid < B) {
        float r = 0.0f;
#pragma unroll
        for (int l = 0; l < TLANES; ++l) r += partials[l * SPB + tid];
        atomicAdd(&out[sbase + tid], r);   // 2 adds/elem; ulp noise << 2.7 thr
    }
}

extern "C" void kernel_launch(void* const* d_in, const int* in_sizes, int n_in,
                              void* d_out, int out_size, void* d_ws, size_t ws_size,
                              hipStream_t stream)
{
    const float* x          = (const float*)d_in[0];
    const int*   split_idx  = (const int*)d_in[1];
    const float* split_cond = (const float*)d_in[2];
    const float* base_score = (const float*)d_in[3];
    float*       out        = (float*)d_out;

    const int B = out_size;                               // 50000
    xgb_init_kernel<<<(B + 255) / 256, 256, 0, stream>>>(base_score, out, B);

    const int nNodesTotal = NTREES * NNODES;              // 127000
    const int grid = ((B + SPB - 1) / SPB) * NSPLIT;      // 1564

    if (ws_size >= (size_t)nNodesTotal * sizeof(int2)) {
        int2* tree = (int2*)d_ws;
        xgb_pack_kernel<<<(nNodesTotal + 255) / 256, 256, 0, stream>>>(
            split_idx, split_cond, tree, nNodesTotal);
        xgb_forest_kernel<true><<<grid, NTH, 0, stream>>>(
            x, split_idx, split_cond, tree, out, B);
    } else {
        xgb_forest_kernel<false><<<grid, NTH, 0, stream>>>(
            x, split_idx, split_cond, (const int2*)nullptr, out, B);
    }
}

// Round 5
// 201.160 us; speedup vs baseline: 1.9582x; 1.0205x over previous
//
#include <hip/hip_runtime.h>
#include <stdint.h>

// XGBoost forest inference: B=50000, F=256, T=1000, depth=6, 127 nodes/tree.
// v5: per-level pipe assignment.
//   levels 0-2: VMEM from packed top[t] (64B line; per-lane node select via
//               ADDRESS within one line -> 1 transaction/level, no cndmask)
//   levels 3-5: LDS (divergent reads belong in LDS), mid[t]=56 int2 staged
//               via global_load_lds (linear, issue-free), double-buffered
//   leaf:       VMEM from packed leaf[t] (256B = 4 lines, compact)
// LDS/visit 91->59cy. 122KB LDS -> 1 block/CU, 8 waves, W=8 -> 64 dep-chains
// vs ~35 needed. Makespan: NSPLIT=2 + atomicAdd (1564 blocks, x1.15 quant).
// v2/v4 lesson: deep-level divergent VMEM = TA serialization -> keep in LDS.
// v3 lesson: scalar-pipe select chains + low ILP = latency-starved.

#define NFEAT   256
#define NNODES  127
#define NTREES  1000
#define SPB     64       // samples per block (= lanes per wave)
#define NTH     512      // 8 waves
#define TLANES  8        // tree lanes (tid>>6)
#define NSPLIT  2
#define TSPLIT  500      // trees per split unit
#define TILE_T  64       // trees per mid-tile
#define MID_DW  112      // dwords per tree in mid (56 int2)
#define MID_B   448      // bytes per tree in mid
#define NTILES  8        // ceil(500/64), last tile = 52 trees
#define CHUNKS  28       // TILE_T*MID_B / 1024

// d_ws layout (1024-tree padded so tile staging may over-read safely)
#define TOP_OFF  0                       // int2 [1024][8]   = 64 KB
#define LEAF_OFF (65536)                 // float[1024][64]  = 256 KB
#define MID_OFF  (65536 + 262144)        // int2 [1024][56]  = 448 KB
#define WS_NEED  (65536 + 262144 + 458752)

typedef __attribute__((address_space(1))) const unsigned char ga_u8;
typedef __attribute__((address_space(3))) unsigned char       la_u8;

__global__ void xgb_init_kernel(const float* __restrict__ base_score,
                                float* __restrict__ out, int B)
{
    const int i = blockIdx.x * 256 + threadIdx.x;
    if (i < B) out[i] = base_score[0];
}

__global__ void xgb_pack_kernel(const int* __restrict__ idx,
                                const float* __restrict__ cond,
                                char* __restrict__ ws, int n)
{
    const int i = blockIdx.x * 256 + threadIdx.x;
    if (i >= n) return;
    const int t  = i / NNODES;
    const int nd = i - t * NNODES;
    const int   f = idx[i];
    const float c = cond[i];
    if (nd < 7) {
        ((int2*)(ws + TOP_OFF))[t * 8 + nd] = make_int2(f, __float_as_int(c));
    } else if (nd < 63) {
        ((int2*)(ws + MID_OFF))[t * 56 + (nd - 7)] = make_int2(f, __float_as_int(c));
    } else {
        ((float*)(ws + LEAF_OFF))[t * 64 + (nd - 63)] = c;
    }
}

// stage one 64-tree mid tile (28 KB) into LDS buf via global_load_lds.
// LDS dest = wave-uniform base (+ implicit lane*16); global src per-lane.
__device__ __forceinline__ void stage_mid(const char* __restrict__ midG,
                                          int treeBase, int* buf,
                                          int wid, int lane)
{
    const char* src = midG + (size_t)treeBase * MID_B;
    for (int c = wid; c < CHUNKS; c += TLANES) {
        const char* g = src + c * 1024 + lane * 16;
        char*       l = (char*)buf + c * 1024;
#if __has_builtin(__builtin_amdgcn_global_load_lds)
        __builtin_amdgcn_global_load_lds((ga_u8*)(uintptr_t)g,
                                         (la_u8*)(uintptr_t)l, 16, 0, 0);
#else
        *reinterpret_cast<int4*>(l + lane * 16) =
            *reinterpret_cast<const int4*>(g);
#endif
    }
}

template <int W>
__device__ __forceinline__ void walk(const int2*  __restrict__ topP,
                                     const float* __restrict__ leafG,
                                     const int*   __restrict__ mbuf,
                                     const float* __restrict__ xs,
                                     int tbase, int tlane, int k, float& acc)
{
    int node[W], tg[W], lb[W];
#pragma unroll
    for (int j = 0; j < W; ++j) {
        const int tl = tlane + (k + j) * TLANES;    // tile-local tree
        tg[j] = tbase + tl;                         // global tree
        lb[j] = tl * MID_DW;
        node[j] = 0;
    }
    // levels 0-2: per-lane VMEM inside one 64B line per tree
#pragma unroll
    for (int d = 0; d < 3; ++d) {
#pragma unroll
        for (int j = 0; j < W; ++j) {
            const int2  nd = topP[tg[j] * 8 + node[j]];
            const float xv = xs[nd.x * SPB];
            node[j] = 2 * node[j] + 1 +
                      (int)((xv - __int_as_float(nd.y)) > 0.0f);
        }
    }
    // levels 3-5: LDS mid tile (nodes 7..62)
#pragma unroll
    for (int d = 3; d < 6; ++d) {
#pragma unroll
        for (int j = 0; j < W; ++j) {
            const int2 nd = *reinterpret_cast<const int2*>(
                &mbuf[lb[j] + 2 * (node[j] - 7)]);
            const float xv = xs[nd.x * SPB];
            node[j] = 2 * node[j] + 1 +
                      (int)((xv - __int_as_float(nd.y)) > 0.0f);
        }
    }
    // leaf: VMEM, 4 lines per tree
#pragma unroll
    for (int j = 0; j < W; ++j)
        acc += leafG[tg[j] * 64 + (node[j] - 63)];
}

__global__ __launch_bounds__(NTH, 1) void xgb_forest_kernel(
    const float* __restrict__ x,
    const char*  __restrict__ ws,
    float* __restrict__ out, int B)
{
    __shared__ float xT[NFEAT * SPB];                    // 64 KB
    __shared__ __align__(16) int midL[2 * TILE_T * MID_DW]; // 56 KB
    __shared__ float partials[TLANES * SPB];             //  2 KB

    const int2*  topP  = (const int2*)(ws + TOP_OFF);
    const float* leafG = (const float*)(ws + LEAF_OFF);
    const char*  midG  = ws + MID_OFF;

    const int tid   = threadIdx.x;
    const int sbase = (blockIdx.x >> 1) * SPB;
    const int t0    = (blockIdx.x & 1) * TSPLIT;
    const int s     = tid & 63;
    const int tlane = tid >> 6;   // == wave id

    // issue tile-0 staging first so it flies under the x-staging
    stage_mid(midG, t0, midL, tlane, s);

    // ---- stage x tile, transposed (gather bank = sample%32, conflict-free)
    {
        const int sq = tid & 15;
        const int cg = tid >> 4;               // 0..31
        for (int rg = 0; rg < 4; ++rg) {
            const int  sl = rg * 16 + sq;
            const bool ok = (sbase + sl) < B;
            for (int ci = 0; ci < 2; ++ci) {
                const int c4 = ci * 32 + cg;
                float4 v = make_float4(0.f, 0.f, 0.f, 0.f);
                if (ok)
                    v = *reinterpret_cast<const float4*>(
                        &x[(size_t)(sbase + sl) * NFEAT + c4 * 4]);
                xT[(c4 * 4 + 0) * SPB + sl] = v.x;
                xT[(c4 * 4 + 1) * SPB + sl] = v.y;
                xT[(c4 * 4 + 2) * SPB + sl] = v.z;
                xT[(c4 * 4 + 3) * SPB + sl] = v.w;
            }
        }
    }
    __syncthreads();   // drains vmcnt(0)+lgkmcnt(0): xT and tile 0 ready

    const float* xs = &xT[s];
    float acc = 0.0f;

    for (int t = 0; t < NTILES; ++t) {
        if (t + 1 < NTILES)   // prefetch next tile into the other buffer
            stage_mid(midG, t0 + (t + 1) * TILE_T,
                      midL + ((t + 1) & 1) * (TILE_T * MID_DW), tlane, s);

        const int* mbuf  = midL + (t & 1) * (TILE_T * MID_DW);
        const int  tbase = t0 + t * TILE_T;
        const int  nT    = min(TILE_T, TSPLIT - t * TILE_T);   // 64 / 52
        const int  kmax  = ((nT - 1 - tlane) >> 3) + 1;        // wave-uniform

        int k = 0;
        for (; k + 8 <= kmax; k += 8) walk<8>(topP, leafG, mbuf, xs, tbase, tlane, k, acc);
        for (; k + 4 <= kmax; k += 4) walk<4>(topP, leafG, mbuf, xs, tbase, tlane, k, acc);
        for (; k + 2 <= kmax; k += 2) walk<2>(topP, leafG, mbuf, xs, tbase, tlane, k, acc);
        for (; k < kmax; ++k)         walk<1>(topP, leafG, mbuf, xs, tbase, tlane, k, acc);

        __syncthreads();   // walkers done with mbuf; next tile's loads drained
    }

    partials[tlane * SPB + s] = acc;
    __syncthreads();
    if (tid < SPB && sbase + tid < B) {
        float r = 0.0f;
#pragma unroll
        for (int l = 0; l < TLANES; ++l) r += partials[l * SPB + tid];
        atomicAdd(&out[sbase + tid], r);   // 2 adds/elem; ulp noise << 2.7 thr
    }
}

// never expected to run (ws_size >= 1 MB observed); correctness insurance.
__global__ void xgb_naive_kernel(const float* __restrict__ x,
                                 const int*   __restrict__ split_idx,
                                 const float* __restrict__ split_cond,
                                 const float* __restrict__ base_score,
                                 float* __restrict__ out, int B)
{
    const int sI = blockIdx.x * 256 + threadIdx.x;
    if (sI >= B) return;
    float acc = base_score[0];
    for (int t = 0; t < NTREES; ++t) {
        int node = 0;
        for (int d = 0; d < 6; ++d) {
            const int g = t * NNODES + node;
            const float xv = x[(size_t)sI * NFEAT + split_idx[g]];
            node = 2 * node + 1 + (int)((xv - split_cond[g]) > 0.0f);
        }
        acc += split_cond[t * NNODES + node];
    }
    out[sI] = acc;
}

extern "C" void kernel_launch(void* const* d_in, const int* in_sizes, int n_in,
                              void* d_out, int out_size, void* d_ws, size_t ws_size,
                              hipStream_t stream)
{
    const float* x          = (const float*)d_in[0];
    const int*   split_idx  = (const int*)d_in[1];
    const float* split_cond = (const float*)d_in[2];
    const float* base_score = (const float*)d_in[3];
    float*       out        = (float*)d_out;

    const int B = out_size;                               // 50000

    if (ws_size < (size_t)WS_NEED) {
        xgb_naive_kernel<<<(B + 255) / 256, 256, 0, stream>>>(
            x, split_idx, split_cond, base_score, out, B);
        return;
    }

    xgb_init_kernel<<<(B + 255) / 256, 256, 0, stream>>>(base_score, out, B);

    const int nNodesTotal = NTREES * NNODES;              // 127000
    xgb_pack_kernel<<<(nNodesTotal + 255) / 256, 256, 0, stream>>>(
        split_idx, split_cond, (char*)d_ws, nNodesTotal);

    const int grid = ((B + SPB - 1) / SPB) * NSPLIT;      // 1564
    xgb_forest_kernel<<<grid, NTH, 0, stream>>>(x, (const char*)d_ws, out, B);
}